// Round 1
// baseline (437.714 us; speedup 1.0000x reference)
//
#include <hip/hip_runtime.h>
#include <math.h>

#define BATCH 4
#define SEQ 2048
#define DMODEL 128
#define DINNER 256
#define DSTATE 16
#define DTRANK 8
#define DFF 256
#define NCH 64
#define CSZ 32
#define LN_EPS 1e-5f
#define NROW (BATCH*SEQ)

__device__ __forceinline__ float sigm(float v){ return 1.0f/(1.0f+__expf(-v)); }
#define DOT4(acc,a,b) acc = fmaf((a).x,(b).x, fmaf((a).y,(b).y, fmaf((a).z,(b).z, fmaf((a).w,(b).w,(acc)))))

// ---------------- K1: dual in-projection  xz = x @ [mf_in_w; mb_in_w]^T ----------------
// grid (512, 4), block 256. 16 rows x 256 cols per block, 4x4 register tile per thread.
__global__ __launch_bounds__(256) void k1_inproj(
    const float* __restrict__ x, const float* __restrict__ wf, const float* __restrict__ wb,
    float* __restrict__ xc, float* __restrict__ zz)
{
  __shared__ __align__(16) float xs[16][DMODEL];
  const int t = threadIdx.x;
  const int r0 = blockIdx.x*16;
  {
    const int r = t>>4, k = (t&15)*8;
    const float* src = x + (size_t)(r0+r)*DMODEL + k;
    *(float4*)&xs[r][k]   = *(const float4*)(src);
    *(float4*)&xs[r][k+4] = *(const float4*)(src+4);
  }
  __syncthreads();
  const int ct = t&63, rg4 = t>>6;
  const int c0 = blockIdx.y*256 + ct*4;      // global col in [0,1024)
  const int dir = c0>>9;                     // 0: mf, 1: mb
  const int wrow = c0&511;                   // row in in_w
  const float* wbase = (dir? wb : wf) + (size_t)wrow*DMODEL;
  float acc[4][4];
  #pragma unroll
  for (int j=0;j<4;j++){ acc[j][0]=acc[j][1]=acc[j][2]=acc[j][3]=0.f; }
  #pragma unroll 4
  for (int k=0;k<DMODEL;k+=4){
    float4 w0 = *(const float4*)(wbase + 0*DMODEL + k);
    float4 w1 = *(const float4*)(wbase + 1*DMODEL + k);
    float4 w2 = *(const float4*)(wbase + 2*DMODEL + k);
    float4 w3 = *(const float4*)(wbase + 3*DMODEL + k);
    #pragma unroll
    for (int j=0;j<4;j++){
      float4 xv = *(const float4*)&xs[rg4*4+j][k];
      DOT4(acc[j][0], xv, w0);
      DOT4(acc[j][1], xv, w1);
      DOT4(acc[j][2], xv, w2);
      DOT4(acc[j][3], xv, w3);
    }
  }
  const int kind = (c0>>8)&1;                // 0: xc, 1: z
  const int dd = c0&255;
  float* dst0 = (kind? zz : xc);
  #pragma unroll
  for (int j=0;j<4;j++){
    const int rg = r0 + rg4*4 + j;
    const int b = rg>>11, l = rg&(SEQ-1);
    *(float4*)(dst0 + (((size_t)(dir*BATCH+b)*SEQ + l)*DINNER + dd)) =
        make_float4(acc[j][0],acc[j][1],acc[j][2],acc[j][3]);
  }
}

// ---------------- K2: causal/anti-causal conv + silu + xproj + dt ----------------
// grid (SEQ, BATCH, 2), block 256 (thread = d_inner channel)
__global__ __launch_bounds__(256) void k2_conv_xproj(
    const float* __restrict__ xc,
    const float* __restrict__ cwf, const float* __restrict__ cbf,
    const float* __restrict__ cwb, const float* __restrict__ cbb,
    const float* __restrict__ xpf, const float* __restrict__ xpb,
    const float* __restrict__ dtwf, const float* __restrict__ dtbf,
    const float* __restrict__ dtwb, const float* __restrict__ dtbb,
    float* __restrict__ u, float* __restrict__ dto, float* __restrict__ bco)
{
  const int l = blockIdx.x, b = blockIdx.y, dir = blockIdx.z;
  const int d = threadIdx.x;
  __shared__ __align__(16) float su[DINNER];
  __shared__ float sdbc[DTRANK + 2*DSTATE];
  const float* cw = dir? cwb : cwf;
  const float* cb = dir? cbb : cbf;
  const float* xcb_ = xc + (size_t)(dir*BATCH + b)*SEQ*DINNER;
  float accv = cb[d];
  #pragma unroll
  for (int k=0;k<4;k++){
    // forward: sum_k w[k]*xc[l-3+k] ; backward(natural coords): sum_k w[k]*xc[l+3-k]
    int idx = dir? (l + 3 - k) : (l - 3 + k);
    if (idx >= 0 && idx < SEQ) accv = fmaf(cw[d*4+k], xcb_[(size_t)idx*DINNER + d], accv);
  }
  float uv = accv * sigm(accv);
  su[d] = uv;
  const size_t rowoff = ((size_t)(dir*BATCH+b)*SEQ + l);
  u[rowoff*DINNER + d] = uv;
  __syncthreads();
  if (d < DTRANK + 2*DSTATE){
    const float* xp = (dir? xpb : xpf) + (size_t)d*DINNER;
    float a0=0,a1=0,a2=0,a3=0;
    for (int k=0;k<DINNER;k+=4){
      float4 sv = *(const float4*)&su[k];
      float4 wv = *(const float4*)(xp+k);
      a0 = fmaf(sv.x,wv.x,a0); a1 = fmaf(sv.y,wv.y,a1);
      a2 = fmaf(sv.z,wv.z,a2); a3 = fmaf(sv.w,wv.w,a3);
    }
    sdbc[d] = (a0+a1)+(a2+a3);
  }
  __syncthreads();
  const float* dtw = (dir? dtwb : dtwf) + d*DTRANK;
  float pre = (dir? dtbb : dtbf)[d];
  #pragma unroll
  for (int j=0;j<DTRANK;j++) pre = fmaf(sdbc[j], dtw[j], pre);
  float sp = (pre > 20.f) ? pre : log1pf(__expf(pre));
  dto[rowoff*DINNER + d] = sp;
  if (d < 2*DSTATE) bco[rowoff*32 + d] = sdbc[DTRANK + d];
}

// ---------------- K3a: chunk-local scan (S = local end state, P = chunk decay) ----------------
// grid (NCH, BATCH, 2), block 256 (thread = d). h[16] in registers.
__global__ __launch_bounds__(256) void k3_scan1(
    const float* __restrict__ u, const float* __restrict__ dt, const float* __restrict__ bc,
    const float* __restrict__ Alf, const float* __restrict__ Alb,
    float* __restrict__ P, float* __restrict__ S)
{
  const int c = blockIdx.x, b = blockIdx.y, dir = blockIdx.z;
  const int d = threadIdx.x;
  __shared__ float sB[CSZ][DSTATE];
  {
    const int i = threadIdx.x>>3;
    const int s = (threadIdx.x&7)*2;
    const int tn = dir ? (SEQ-1-(c*CSZ+i)) : (c*CSZ+i);
    const float* src = bc + ((size_t)(dir*BATCH+b)*SEQ + tn)*32 + s;
    sB[i][s] = src[0]; sB[i][s+1] = src[1];
  }
  const float* Al = (dir? Alb : Alf) + d*DSTATE;
  float a[DSTATE], h[DSTATE];
  #pragma unroll
  for (int s=0;s<DSTATE;s++){ a[s] = -__expf(Al[s]); h[s]=0.f; }
  float dtsum = 0.f;
  const size_t base = (size_t)(dir*BATCH+b)*SEQ*DINNER + d;
  __syncthreads();
  #pragma unroll 2
  for (int i=0;i<CSZ;i++){
    const int tn = dir ? (SEQ-1-(c*CSZ+i)) : (c*CSZ+i);
    const float dtv = dt[base + (size_t)tn*DINNER];
    const float uv  = u [base + (size_t)tn*DINNER];
    const float dtu = dtv*uv;
    dtsum += dtv;
    #pragma unroll
    for (int s=0;s<DSTATE;s++){
      float dA = __expf(dtv*a[s]);
      h[s] = fmaf(dA, h[s], dtu*sB[i][s]);
    }
  }
  const size_t po = (((size_t)(dir*BATCH+b)*NCH + c)*DINNER + d)*DSTATE;
  #pragma unroll
  for (int s=0;s<DSTATE;s++){ P[po+s] = __expf(a[s]*dtsum); S[po+s] = h[s]; }
}

// ---------------- K3b: sequential combine across chunks; S becomes Hinit in-place ----------------
// grid (16, BATCH, 2), block 256 = 16 d x 16 s
__global__ __launch_bounds__(256) void k3_scan2(const float* __restrict__ P, float* __restrict__ S)
{
  const int dg = blockIdx.x, b = blockIdx.y, dir = blockIdx.z;
  const int d = dg*16 + (threadIdx.x>>4);
  const int s = threadIdx.x&15;
  const size_t base = ((size_t)(dir*BATCH+b)*NCH)*DINNER*DSTATE + (size_t)d*DSTATE + s;
  float H = 0.f;
  for (int c=0;c<NCH;c++){
    const size_t off = base + (size_t)c*(DINNER*DSTATE);
    float p = P[off], sv = S[off];
    S[off] = H;               // Hinit for chunk c
    H = fmaf(p, H, sv);
  }
}

// ---------------- K3c: re-run chunks with correct init, emit y = scan_out + u*D ----------------
__global__ __launch_bounds__(256) void k3_scan3(
    const float* __restrict__ u, const float* __restrict__ dt, const float* __restrict__ bc,
    const float* __restrict__ Alf, const float* __restrict__ Alb,
    const float* __restrict__ Df, const float* __restrict__ Db,
    const float* __restrict__ Hin, float* __restrict__ y)
{
  const int c = blockIdx.x, b = blockIdx.y, dir = blockIdx.z;
  const int d = threadIdx.x;
  __shared__ __align__(16) float sBC[CSZ][32];
  {
    const int i = threadIdx.x>>3;
    const int j = (threadIdx.x&7)*4;
    const int tn = dir ? (SEQ-1-(c*CSZ+i)) : (c*CSZ+i);
    *(float4*)&sBC[i][j] = *(const float4*)(bc + ((size_t)(dir*BATCH+b)*SEQ + tn)*32 + j);
  }
  const float* Al = (dir? Alb : Alf) + d*DSTATE;
  float a[DSTATE], h[DSTATE];
  const size_t po = (((size_t)(dir*BATCH+b)*NCH + c)*DINNER + d)*DSTATE;
  #pragma unroll
  for (int s=0;s<DSTATE;s++){ a[s] = -__expf(Al[s]); h[s] = Hin[po+s]; }
  const float Dv = (dir? Db : Df)[d];
  const size_t base = (size_t)(dir*BATCH+b)*SEQ*DINNER + d;
  __syncthreads();
  #pragma unroll 2
  for (int i=0;i<CSZ;i++){
    const int tn = dir ? (SEQ-1-(c*CSZ+i)) : (c*CSZ+i);
    const float dtv = dt[base + (size_t)tn*DINNER];
    const float uv  = u [base + (size_t)tn*DINNER];
    const float dtu = dtv*uv;
    float yv = 0.f;
    #pragma unroll
    for (int s=0;s<DSTATE;s++){
      float dA = __expf(dtv*a[s]);
      h[s] = fmaf(dA, h[s], dtu*sBC[i][s]);
      yv = fmaf(h[s], sBC[i][DSTATE+s], yv);
    }
    y[base + (size_t)tn*DINNER] = fmaf(uv, Dv, yv);
  }
}

// ---------------- K4: gate + dual out-proj + dual LN + sum ----------------
// grid (512), block 256. 16 rows per block; cols 0..127 = forward LN, 128..255 = backward LN.
__global__ __launch_bounds__(256) void k4_outproj_ln(
    const float* __restrict__ y, const float* __restrict__ zz, const float* __restrict__ x,
    const float* __restrict__ owf, const float* __restrict__ owb,
    const float* __restrict__ lfg, const float* __restrict__ lfb,
    const float* __restrict__ lbg, const float* __restrict__ lbb,
    float* __restrict__ outb)
{
  __shared__ __align__(16) float gs[16][2*DINNER];
  const int t = threadIdx.x;
  const int r0 = blockIdx.x*16;
  #pragma unroll
  for (int it=0; it<8; it++){
    const int e = it*256 + t;          // float4 index over 16x512
    const int row = e>>7;
    const int col4 = (e&127)*4;
    const int dir = col4>>8;
    const int d0 = col4&255;
    const int rg = r0+row, bb = rg>>11, l = rg&(SEQ-1);
    const size_t off = ((size_t)(dir*BATCH+bb)*SEQ + l)*DINNER + d0;
    float4 yv = *(const float4*)(y + off);
    float4 zv = *(const float4*)(zz + off);
    float4 g;
    g.x = yv.x * (zv.x*sigm(zv.x));
    g.y = yv.y * (zv.y*sigm(zv.y));
    g.z = yv.z * (zv.z*sigm(zv.z));
    g.w = yv.w * (zv.w*sigm(zv.w));
    *(float4*)&gs[row][col4] = g;
  }
  __syncthreads();
  const int ct = t&63, rg4 = t>>6;
  const int c0 = ct*4;                 // 0..255
  const int dir = c0>>7;
  const int j0 = c0&127;
  const float* wbase = (dir? owb : owf) + (size_t)j0*DINNER;
  float acc[4][4];
  #pragma unroll
  for (int j=0;j<4;j++){acc[j][0]=acc[j][1]=acc[j][2]=acc[j][3]=0.f;}
  #pragma unroll 2
  for (int k=0;k<DINNER;k+=4){
    float4 w0 = *(const float4*)(wbase + 0*DINNER + k);
    float4 w1 = *(const float4*)(wbase + 1*DINNER + k);
    float4 w2 = *(const float4*)(wbase + 2*DINNER + k);
    float4 w3 = *(const float4*)(wbase + 3*DINNER + k);
    #pragma unroll
    for (int j=0;j<4;j++){
      float4 gv = *(const float4*)&gs[rg4*4+j][dir*DINNER + k];
      DOT4(acc[j][0], gv, w0);
      DOT4(acc[j][1], gv, w1);
      DOT4(acc[j][2], gv, w2);
      DOT4(acc[j][3], gv, w3);
    }
  }
  const float4 gam = *(const float4*)((dir? lbg : lfg) + j0);
  const float4 bet = *(const float4*)((dir? lbb : lfb) + j0);
  #pragma unroll
  for (int j=0;j<4;j++){
    const int rg = r0 + rg4*4 + j;
    float4 xv = *(const float4*)(x + (size_t)rg*DMODEL + j0);
    float o0 = acc[j][0]+xv.x, o1 = acc[j][1]+xv.y, o2 = acc[j][2]+xv.z, o3 = acc[j][3]+xv.w;
    float s1 = (o0+o1)+(o2+o3);
    float s2 = fmaf(o0,o0,fmaf(o1,o1,fmaf(o2,o2,o3*o3)));
    #pragma unroll
    for (int m=1;m<32;m<<=1){
      s1 += __shfl_xor(s1, m, 64);
      s2 += __shfl_xor(s2, m, 64);
    }
    const float mu = s1*(1.0f/DMODEL);
    const float var = s2*(1.0f/DMODEL) - mu*mu;
    const float rs = rsqrtf(var + LN_EPS);
    float v0 = (o0-mu)*rs*gam.x + bet.x;
    float v1 = (o1-mu)*rs*gam.y + bet.y;
    float v2 = (o2-mu)*rs*gam.z + bet.z;
    float v3 = (o3-mu)*rs*gam.w + bet.w;
    v0 += __shfl_xor(v0, 32, 64);
    v1 += __shfl_xor(v1, 32, 64);
    v2 += __shfl_xor(v2, 32, 64);
    v3 += __shfl_xor(v3, 32, 64);
    if (ct < 32)
      *(float4*)(outb + (size_t)rg*DMODEL + j0) = make_float4(v0,v1,v2,v3);
  }
}

// ---------------- K5: FFN (relu GEMM1 -> GEMM2) + residual + final LN ----------------
__global__ __launch_bounds__(256) void k5_ffn(
    const float* __restrict__ outb,
    const float* __restrict__ w1, const float* __restrict__ b1,
    const float* __restrict__ w2, const float* __restrict__ b2,
    const float* __restrict__ lg, const float* __restrict__ lb,
    float* __restrict__ dout)
{
  __shared__ __align__(16) float so[16][DMODEL];
  __shared__ __align__(16) float sh[16][DFF];
  const int t = threadIdx.x;
  const int r0 = blockIdx.x*16;
  #pragma unroll
  for (int it=0; it<2; it++){
    const int e = it*256 + t;
    const int row = e>>5;
    const int col4 = (e&31)*4;
    *(float4*)&so[row][col4] = *(const float4*)(outb + (size_t)(r0+row)*DMODEL + col4);
  }
  __syncthreads();
  const int ct = t&63, rg4 = t>>6;
  {
    const int c0 = ct*4;
    const float* wbase = w1 + (size_t)c0*DMODEL;
    float acc[4][4];
    #pragma unroll
    for (int j=0;j<4;j++){acc[j][0]=acc[j][1]=acc[j][2]=acc[j][3]=0.f;}
    #pragma unroll 2
    for (int k=0;k<DMODEL;k+=4){
      float4 w0v = *(const float4*)(wbase + 0*DMODEL + k);
      float4 w1v = *(const float4*)(wbase + 1*DMODEL + k);
      float4 w2v = *(const float4*)(wbase + 2*DMODEL + k);
      float4 w3v = *(const float4*)(wbase + 3*DMODEL + k);
      #pragma unroll
      for (int j=0;j<4;j++){
        float4 gv = *(const float4*)&so[rg4*4+j][k];
        DOT4(acc[j][0], gv, w0v);
        DOT4(acc[j][1], gv, w1v);
        DOT4(acc[j][2], gv, w2v);
        DOT4(acc[j][3], gv, w3v);
      }
    }
    float4 bb = *(const float4*)(b1 + c0);
    #pragma unroll
    for (int j=0;j<4;j++){
      sh[rg4*4+j][c0+0] = fmaxf(acc[j][0]+bb.x, 0.f);
      sh[rg4*4+j][c0+1] = fmaxf(acc[j][1]+bb.y, 0.f);
      sh[rg4*4+j][c0+2] = fmaxf(acc[j][2]+bb.z, 0.f);
      sh[rg4*4+j][c0+3] = fmaxf(acc[j][3]+bb.w, 0.f);
    }
  }
  __syncthreads();
  {
    const int c0 = ct*2;
    const float* wr0 = w2 + (size_t)c0*DFF;
    const float* wr1 = w2 + (size_t)(c0+1)*DFF;
    float a0[4] = {0,0,0,0}, a1[4] = {0,0,0,0};
    #pragma unroll 2
    for (int k=0;k<DFF;k+=4){
      float4 wv0 = *(const float4*)(wr0+k);
      float4 wv1 = *(const float4*)(wr1+k);
      #pragma unroll
      for (int j=0;j<4;j++){
        float4 hv = *(const float4*)&sh[rg4*4+j][k];
        DOT4(a0[j], hv, wv0);
        DOT4(a1[j], hv, wv1);
      }
    }
    const float bb0 = b2[c0], bb1 = b2[c0+1];
    const float g0 = lg[c0], g1 = lg[c0+1], be0 = lb[c0], be1 = lb[c0+1];
    #pragma unroll
    for (int j=0;j<4;j++){
      const int rg = r0 + rg4*4 + j;
      float o0 = a0[j] + bb0 + so[rg4*4+j][c0];
      float o1 = a1[j] + bb1 + so[rg4*4+j][c0+1];
      float s1 = o0+o1, s2 = fmaf(o0,o0,o1*o1);
      #pragma unroll
      for (int m=1;m<64;m<<=1){ s1 += __shfl_xor(s1,m,64); s2 += __shfl_xor(s2,m,64); }
      float mu = s1*(1.0f/DMODEL);
      float var = s2*(1.0f/DMODEL) - mu*mu;
      float rs = rsqrtf(var+LN_EPS);
      float v0 = (o0-mu)*rs*g0 + be0;
      float v1 = (o1-mu)*rs*g1 + be1;
      *(float2*)(dout + (size_t)rg*DMODEL + c0) = make_float2(v0,v1);
    }
  }
}

extern "C" void kernel_launch(void* const* d_in, const int* in_sizes, int n_in,
                              void* d_out, int out_size, void* d_ws, size_t ws_size,
                              hipStream_t stream)
{
  const float* x      = (const float*)d_in[0];
  const float* mf_inw = (const float*)d_in[1];
  const float* mf_cw  = (const float*)d_in[2];
  const float* mf_cb  = (const float*)d_in[3];
  const float* mf_xp  = (const float*)d_in[4];
  const float* mf_dtw = (const float*)d_in[5];
  const float* mf_dtb = (const float*)d_in[6];
  const float* mf_Al  = (const float*)d_in[7];
  const float* mf_D   = (const float*)d_in[8];
  const float* mf_ow  = (const float*)d_in[9];
  const float* mb_inw = (const float*)d_in[10];
  const float* mb_cw  = (const float*)d_in[11];
  const float* mb_cb  = (const float*)d_in[12];
  const float* mb_xp  = (const float*)d_in[13];
  const float* mb_dtw = (const float*)d_in[14];
  const float* mb_dtb = (const float*)d_in[15];
  const float* mb_Al  = (const float*)d_in[16];
  const float* mb_D   = (const float*)d_in[17];
  const float* mb_ow  = (const float*)d_in[18];
  const float* lfg    = (const float*)d_in[19];
  const float* lfb    = (const float*)d_in[20];
  const float* lbg    = (const float*)d_in[21];
  const float* lbb    = (const float*)d_in[22];
  const float* lng    = (const float*)d_in[23];
  const float* lnb    = (const float*)d_in[24];
  const float* fw1    = (const float*)d_in[25];
  const float* fb1    = (const float*)d_in[26];
  const float* fw2    = (const float*)d_in[27];
  const float* fb2    = (const float*)d_in[28];

  float* ws = (float*)d_ws;
  const size_t n_big = (size_t)2*BATCH*SEQ*DINNER;        // 4,194,304 floats
  const size_t n_bc  = (size_t)2*BATCH*SEQ*32;            //   524,288
  const size_t n_ps  = (size_t)2*BATCH*NCH*DINNER*DSTATE; // 2,097,152
  float* xc   = ws;               // [2][B][L][256]  (later reused as y)
  float* zz   = xc + n_big;       // [2][B][L][256]
  float* uu   = zz + n_big;       // [2][B][L][256]
  float* dtt  = uu + n_big;       // [2][B][L][256]
  float* bc   = dtt + n_big;      // [2][B][L][32]  (B then C)
  float* P    = bc + n_bc;        // [2][B][NCH][256][16]
  float* S    = P + n_ps;         // [2][B][NCH][256][16] -> Hinit after scan2
  float* outb = S + n_ps;         // [B][L][128]
  float* yy   = xc;               // reuse: xc dead after k2

  k1_inproj<<<dim3(NROW/16, 4), 256, 0, stream>>>(x, mf_inw, mb_inw, xc, zz);
  k2_conv_xproj<<<dim3(SEQ, BATCH, 2), 256, 0, stream>>>(xc,
      mf_cw, mf_cb, mb_cw, mb_cb, mf_xp, mb_xp,
      mf_dtw, mf_dtb, mb_dtw, mb_dtb, uu, dtt, bc);
  k3_scan1<<<dim3(NCH, BATCH, 2), 256, 0, stream>>>(uu, dtt, bc, mf_Al, mb_Al, P, S);
  k3_scan2<<<dim3(DINNER/16, BATCH, 2), 256, 0, stream>>>(P, S);
  k3_scan3<<<dim3(NCH, BATCH, 2), 256, 0, stream>>>(uu, dtt, bc, mf_Al, mb_Al, mf_D, mb_D, S, yy);
  k4_outproj_ln<<<dim3(NROW/16), 256, 0, stream>>>(yy, zz, x, mf_ow, mb_ow,
      lfg, lfb, lbg, lbb, outb);
  k5_ffn<<<dim3(NROW/16), 256, 0, stream>>>(outb, fw1, fb1, fw2, fb2, lng, lnb, (float*)d_out);
}

// Round 2
// 206.724 us; speedup vs baseline: 2.1174x; 2.1174x over previous
//
#include <hip/hip_runtime.h>
#include <math.h>

#define BATCH 4
#define SEQ 2048
#define DMODEL 128
#define DINNER 256
#define DSTATE 16
#define DTRANK 8
#define DFF 256
#define NCH 64
#define CSZ 32
#define LN_EPS 1e-5f
#define NROW (BATCH*SEQ)

__device__ __forceinline__ float sigm(float v){ return 1.0f/(1.0f+__expf(-v)); }
#define DOT4(acc,a,b) acc = fmaf((a).x,(b).x, fmaf((a).y,(b).y, fmaf((a).z,(b).z, fmaf((a).w,(b).w,(acc)))))

// ================= K1: dual in-projection, 64x64 LDS-tiled GEMM =================
// M=8192, N=1024 (dir*512 + 256*kind + dd), K=128. grid (128,16), block 256.
__global__ __launch_bounds__(256) void k1_inproj(
    const float* __restrict__ x, const float* __restrict__ wf, const float* __restrict__ wb,
    float* __restrict__ xc, float* __restrict__ zz)
{
  __shared__ float4 xs4[64][16];
  __shared__ float4 wt4[64][16];
  const int t = threadIdx.x;
  const int tx = t&15, ty = t>>4;
  const int r0 = blockIdx.x*64;
  const int c0b = blockIdx.y*64;
  const int dir = c0b>>9;
  const float* wbase = (dir? wb : wf) + (size_t)(c0b&511)*DMODEL;

  float acc[4][4];
  #pragma unroll
  for (int j=0;j<4;j++){acc[j][0]=acc[j][1]=acc[j][2]=acc[j][3]=0.f;}

  for (int kc=0; kc<DMODEL; kc+=64){
    #pragma unroll
    for (int p=0;p<4;p++){
      const int row = p*16 + ty;
      const int fs = tx ^ ((row>>2)&15);
      xs4[row][fs] = *(const float4*)(x + (size_t)(r0+row)*DMODEL + kc + tx*4);
      wt4[row][fs] = *(const float4*)(wbase + (size_t)row*DMODEL + kc + tx*4);
    }
    __syncthreads();
    #pragma unroll 8
    for (int f=0; f<16; f++){
      float4 a0 = xs4[ty*4+0][f^ty];
      float4 a1 = xs4[ty*4+1][f^ty];
      float4 a2 = xs4[ty*4+2][f^ty];
      float4 a3 = xs4[ty*4+3][f^ty];
      float4 b0 = wt4[tx*4+0][f^tx];
      float4 b1 = wt4[tx*4+1][f^tx];
      float4 b2 = wt4[tx*4+2][f^tx];
      float4 b3 = wt4[tx*4+3][f^tx];
      DOT4(acc[0][0],a0,b0); DOT4(acc[0][1],a0,b1); DOT4(acc[0][2],a0,b2); DOT4(acc[0][3],a0,b3);
      DOT4(acc[1][0],a1,b0); DOT4(acc[1][1],a1,b1); DOT4(acc[1][2],a1,b2); DOT4(acc[1][3],a1,b3);
      DOT4(acc[2][0],a2,b0); DOT4(acc[2][1],a2,b1); DOT4(acc[2][2],a2,b2); DOT4(acc[2][3],a2,b3);
      DOT4(acc[3][0],a3,b0); DOT4(acc[3][1],a3,b1); DOT4(acc[3][2],a3,b2); DOT4(acc[3][3],a3,b3);
    }
    __syncthreads();
  }
  const int kind = (c0b>>8)&1;
  const int dd = (c0b&255) + tx*4;
  float* dst = kind? zz : xc;
  #pragma unroll
  for (int j=0;j<4;j++){
    const int rg = r0 + ty*4 + j;
    const int b = rg>>11, l = rg&(SEQ-1);
    *(float4*)(dst + (((size_t)(dir*BATCH+b)*SEQ + l)*DINNER + dd)) =
      make_float4(acc[j][0],acc[j][1],acc[j][2],acc[j][3]);
  }
}

// ================= K2: conv + silu + xproj + dt, 16 timesteps per block =================
// grid (128, BATCH, 2), block 256.
__global__ __launch_bounds__(256) void k2_conv_xproj(
    const float* __restrict__ xc,
    const float* __restrict__ cwf, const float* __restrict__ cbf,
    const float* __restrict__ cwb, const float* __restrict__ cbb,
    const float* __restrict__ xpf, const float* __restrict__ xpb,
    const float* __restrict__ dtwf, const float* __restrict__ dtbf,
    const float* __restrict__ dtwb, const float* __restrict__ dtbb,
    float* __restrict__ u, float* __restrict__ dto, float* __restrict__ bco)
{
  __shared__ __align__(16) float sxp[40*260];   // first used as sxc[19][256]
  __shared__ __align__(16) float su[16][256];
  __shared__ float sdbc[16][48];
  const int t = threadIdx.x;
  const int l0 = blockIdx.x*16;
  const int b = blockIdx.y, dir = blockIdx.z;
  const float* xcb = xc + (size_t)(dir*BATCH+b)*SEQ*DINNER;
  const int lbase = dir ? l0 : l0-3;
  for (int e = t; e < 19*64; e += 256){
    const int row = e>>6, f4i = e&63;
    const int l = lbase + row;
    float4 v = make_float4(0.f,0.f,0.f,0.f);
    if (l >= 0 && l < SEQ) v = *(const float4*)(xcb + (size_t)l*DINNER + f4i*4);
    *(float4*)&sxp[row*256 + f4i*4] = v;
  }
  __syncthreads();
  const int d = t;
  {
    const float4 cw4 = *(const float4*)((dir? cwb : cwf) + d*4);
    const float cbv = (dir? cbb : cbf)[d];
    #pragma unroll
    for (int lt=0; lt<16; lt++){
      float a;
      if (dir == 0){
        a = cbv + cw4.x*sxp[(lt+0)*256+d] + cw4.y*sxp[(lt+1)*256+d]
                + cw4.z*sxp[(lt+2)*256+d] + cw4.w*sxp[(lt+3)*256+d];
      } else {
        a = cbv + cw4.x*sxp[(lt+3)*256+d] + cw4.y*sxp[(lt+2)*256+d]
                + cw4.z*sxp[(lt+1)*256+d] + cw4.w*sxp[(lt+0)*256+d];
      }
      float uv = a*sigm(a);
      su[lt][d] = uv;
      u[((size_t)(dir*BATCH+b)*SEQ + l0+lt)*DINNER + d] = uv;
    }
  }
  __syncthreads();
  // stage xproj weights 40x256 into padded 40x260
  {
    const float* xp = dir? xpb : xpf;
    for (int e = t; e < 40*64; e += 256){
      const int row = e>>6, f4i = e&63;
      *(float4*)&sxp[row*260 + f4i*4] = *(const float4*)(xp + (size_t)row*DINNER + f4i*4);
    }
  }
  __syncthreads();
  {
    const int ot = t&63, lg = t>>6;
    if (ot < 40){
      float accv[4] = {0.f,0.f,0.f,0.f};
      #pragma unroll 4
      for (int f4i=0; f4i<64; f4i++){
        const float4 wv = *(const float4*)&sxp[ot*260 + f4i*4];
        #pragma unroll
        for (int li=0; li<4; li++){
          const float4 sv = *(const float4*)&su[lg*4+li][f4i*4];
          DOT4(accv[li], sv, wv);
        }
      }
      #pragma unroll
      for (int li=0; li<4; li++) sdbc[lg*4+li][ot] = accv[li];
    }
  }
  __syncthreads();
  {
    const float* dtw = (dir? dtwb : dtwf) + d*DTRANK;
    const float4 w0 = *(const float4*)(dtw);
    const float4 w1 = *(const float4*)(dtw+4);
    const float dtbv = (dir? dtbb : dtbf)[d];
    #pragma unroll
    for (int lt=0; lt<16; lt++){
      const float* s = sdbc[lt];
      float pre = dtbv + w0.x*s[0]+w0.y*s[1]+w0.z*s[2]+w0.w*s[3]
                       + w1.x*s[4]+w1.y*s[5]+w1.z*s[6]+w1.w*s[7];
      float sp = (pre > 20.f) ? pre : log1pf(__expf(pre));
      dto[((size_t)(dir*BATCH+b)*SEQ + l0+lt)*DINNER + d] = sp;
    }
    if (t < 32){
      #pragma unroll
      for (int lt=0; lt<16; lt++)
        bco[((size_t)(dir*BATCH+b)*SEQ + l0+lt)*32 + t] = sdbc[lt][DTRANK + t];
    }
  }
}

// ================= K3a: chunk-local scan =================
__global__ __launch_bounds__(256) void k3_scan1(
    const float* __restrict__ u, const float* __restrict__ dt, const float* __restrict__ bc,
    const float* __restrict__ Alf, const float* __restrict__ Alb,
    float* __restrict__ P, float* __restrict__ S)
{
  const int c = blockIdx.x, b = blockIdx.y, dir = blockIdx.z;
  const int d = threadIdx.x;
  __shared__ float sB[CSZ][DSTATE];
  {
    const int i = threadIdx.x>>3;
    const int s = (threadIdx.x&7)*2;
    const int tn = dir ? (SEQ-1-(c*CSZ+i)) : (c*CSZ+i);
    const float* src = bc + ((size_t)(dir*BATCH+b)*SEQ + tn)*32 + s;
    sB[i][s] = src[0]; sB[i][s+1] = src[1];
  }
  float al[DSTATE], a[DSTATE], h[DSTATE];
  {
    const float4* Al4 = (const float4*)((dir? Alb : Alf) + d*DSTATE);
    *(float4*)&al[0] = Al4[0]; *(float4*)&al[4] = Al4[1];
    *(float4*)&al[8] = Al4[2]; *(float4*)&al[12] = Al4[3];
  }
  #pragma unroll
  for (int s=0;s<DSTATE;s++){ a[s] = -__expf(al[s]); h[s]=0.f; }
  float dtsum = 0.f;
  const size_t base = (size_t)(dir*BATCH+b)*SEQ*DINNER + d;
  __syncthreads();
  #pragma unroll 2
  for (int i=0;i<CSZ;i++){
    const int tn = dir ? (SEQ-1-(c*CSZ+i)) : (c*CSZ+i);
    const float dtv = dt[base + (size_t)tn*DINNER];
    const float uv  = u [base + (size_t)tn*DINNER];
    const float dtu = dtv*uv;
    dtsum += dtv;
    #pragma unroll
    for (int s=0;s<DSTATE;s++){
      float dA = __expf(dtv*a[s]);
      h[s] = fmaf(dA, h[s], dtu*sB[i][s]);
    }
  }
  const size_t po = (((size_t)(dir*BATCH+b)*NCH + c)*DINNER + d)*DSTATE;
  float pv[DSTATE];
  #pragma unroll
  for (int s=0;s<DSTATE;s++) pv[s] = __expf(a[s]*dtsum);
  #pragma unroll
  for (int q=0;q<4;q++){
    *(float4*)(P+po+q*4) = *(float4*)&pv[q*4];
    *(float4*)(S+po+q*4) = *(float4*)&h[q*4];
  }
}

// ================= K3b: sequential combine across chunks =================
__global__ __launch_bounds__(256) void k3_scan2(const float* __restrict__ P, float* __restrict__ S)
{
  const int dg = blockIdx.x, b = blockIdx.y, dir = blockIdx.z;
  const int d = dg*16 + (threadIdx.x>>4);
  const int s = threadIdx.x&15;
  const size_t base = ((size_t)(dir*BATCH+b)*NCH)*DINNER*DSTATE + (size_t)d*DSTATE + s;
  float H = 0.f;
  for (int c=0;c<NCH;c++){
    const size_t off = base + (size_t)c*(DINNER*DSTATE);
    float p = P[off], sv = S[off];
    S[off] = H;
    H = fmaf(p, H, sv);
  }
}

// ================= K3c: re-run chunks with correct init, emit y =================
__global__ __launch_bounds__(256) void k3_scan3(
    const float* __restrict__ u, const float* __restrict__ dt, const float* __restrict__ bc,
    const float* __restrict__ Alf, const float* __restrict__ Alb,
    const float* __restrict__ Df, const float* __restrict__ Db,
    const float* __restrict__ Hin, float* __restrict__ y)
{
  const int c = blockIdx.x, b = blockIdx.y, dir = blockIdx.z;
  const int d = threadIdx.x;
  __shared__ __align__(16) float sBC[CSZ][32];
  {
    const int i = threadIdx.x>>3;
    const int j = (threadIdx.x&7)*4;
    const int tn = dir ? (SEQ-1-(c*CSZ+i)) : (c*CSZ+i);
    *(float4*)&sBC[i][j] = *(const float4*)(bc + ((size_t)(dir*BATCH+b)*SEQ + tn)*32 + j);
  }
  float al[DSTATE], a[DSTATE], h[DSTATE];
  const size_t po = (((size_t)(dir*BATCH+b)*NCH + c)*DINNER + d)*DSTATE;
  {
    const float4* Al4 = (const float4*)((dir? Alb : Alf) + d*DSTATE);
    *(float4*)&al[0] = Al4[0]; *(float4*)&al[4] = Al4[1];
    *(float4*)&al[8] = Al4[2]; *(float4*)&al[12] = Al4[3];
    const float4* H4 = (const float4*)(Hin + po);
    *(float4*)&h[0] = H4[0]; *(float4*)&h[4] = H4[1];
    *(float4*)&h[8] = H4[2]; *(float4*)&h[12] = H4[3];
  }
  #pragma unroll
  for (int s=0;s<DSTATE;s++) a[s] = -__expf(al[s]);
  const float Dv = (dir? Db : Df)[d];
  const size_t base = (size_t)(dir*BATCH+b)*SEQ*DINNER + d;
  __syncthreads();
  #pragma unroll 2
  for (int i=0;i<CSZ;i++){
    const int tn = dir ? (SEQ-1-(c*CSZ+i)) : (c*CSZ+i);
    const float dtv = dt[base + (size_t)tn*DINNER];
    const float uv  = u [base + (size_t)tn*DINNER];
    const float dtu = dtv*uv;
    float yv = 0.f;
    #pragma unroll
    for (int s=0;s<DSTATE;s++){
      float dA = __expf(dtv*a[s]);
      h[s] = fmaf(dA, h[s], dtu*sBC[i][s]);
      yv = fmaf(h[s], sBC[i][DSTATE+s], yv);
    }
    y[base + (size_t)tn*DINNER] = fmaf(uv, Dv, yv);
  }
}

// ================= K4: gate + out-proj + residual + LN (per dir) =================
// 32 rows x 128 cols per block, K=256 in chunks of 64. grid (256, 2).
__global__ __launch_bounds__(256) void k4_outproj_ln(
    const float* __restrict__ y, const float* __restrict__ zz, const float* __restrict__ x,
    const float* __restrict__ owf, const float* __restrict__ owb,
    const float* __restrict__ lfg, const float* __restrict__ lfb,
    const float* __restrict__ lbg, const float* __restrict__ lbb,
    float* __restrict__ ofb, float* __restrict__ obb)
{
  __shared__ float4 gs4[32][16];
  __shared__ float4 wt4[128][16];
  const int t = threadIdx.x;
  const int tx = t&15, ty = t>>4;
  const int r0 = blockIdx.x*32;
  const int dir = blockIdx.y;
  const float* wbase = dir? owb : owf;

  float acc[2][8];
  #pragma unroll
  for (int j=0;j<2;j++)
    #pragma unroll
    for (int i=0;i<8;i++) acc[j][i]=0.f;

  for (int kc=0; kc<DINNER; kc+=64){
    #pragma unroll
    for (int s=0;s<2;s++){
      const int row = s*16 + ty;
      const int rg = r0 + row;
      const int bb = rg>>11, l = rg&(SEQ-1);
      const size_t off = ((size_t)(dir*BATCH+bb)*SEQ + l)*DINNER + kc + tx*4;
      float4 yv = *(const float4*)(y + off);
      float4 zv = *(const float4*)(zz + off);
      float4 g;
      g.x = yv.x*(zv.x*sigm(zv.x));
      g.y = yv.y*(zv.y*sigm(zv.y));
      g.z = yv.z*(zv.z*sigm(zv.z));
      g.w = yv.w*(zv.w*sigm(zv.w));
      gs4[row][tx ^ ((row>>2)&15)] = g;
    }
    #pragma unroll
    for (int s=0;s<8;s++){
      const int row = s*16 + ty;
      wt4[row][tx ^ ((row>>2)&15)] = *(const float4*)(wbase + (size_t)row*DINNER + kc + tx*4);
    }
    __syncthreads();
    const int gk = (ty*2)>>2;
    #pragma unroll 8
    for (int f=0; f<16; f++){
      float4 a0 = gs4[ty*2+0][f^gk];
      float4 a1 = gs4[ty*2+1][f^gk];
      float4 b0 = wt4[tx*4+0][f^tx];
      float4 b1 = wt4[tx*4+1][f^tx];
      float4 b2 = wt4[tx*4+2][f^tx];
      float4 b3 = wt4[tx*4+3][f^tx];
      float4 b4 = wt4[64+tx*4+0][f^tx];
      float4 b5 = wt4[64+tx*4+1][f^tx];
      float4 b6 = wt4[64+tx*4+2][f^tx];
      float4 b7 = wt4[64+tx*4+3][f^tx];
      DOT4(acc[0][0],a0,b0); DOT4(acc[0][1],a0,b1); DOT4(acc[0][2],a0,b2); DOT4(acc[0][3],a0,b3);
      DOT4(acc[0][4],a0,b4); DOT4(acc[0][5],a0,b5); DOT4(acc[0][6],a0,b6); DOT4(acc[0][7],a0,b7);
      DOT4(acc[1][0],a1,b0); DOT4(acc[1][1],a1,b1); DOT4(acc[1][2],a1,b2); DOT4(acc[1][3],a1,b3);
      DOT4(acc[1][4],a1,b4); DOT4(acc[1][5],a1,b5); DOT4(acc[1][6],a1,b6); DOT4(acc[1][7],a1,b7);
    }
    __syncthreads();
  }
  const float* gam = dir? lbg : lfg;
  const float* bet = dir? lbb : lfb;
  float* dst = dir? obb : ofb;
  const float4 g0 = *(const float4*)(gam + tx*4);
  const float4 g1 = *(const float4*)(gam + 64 + tx*4);
  const float4 e0 = *(const float4*)(bet + tx*4);
  const float4 e1 = *(const float4*)(bet + 64 + tx*4);
  #pragma unroll
  for (int j=0;j<2;j++){
    const int rg = r0 + ty*2 + j;
    float4 x0 = *(const float4*)(x + (size_t)rg*DMODEL + tx*4);
    float4 x1 = *(const float4*)(x + (size_t)rg*DMODEL + 64 + tx*4);
    float o[8];
    o[0]=acc[j][0]+x0.x; o[1]=acc[j][1]+x0.y; o[2]=acc[j][2]+x0.z; o[3]=acc[j][3]+x0.w;
    o[4]=acc[j][4]+x1.x; o[5]=acc[j][5]+x1.y; o[6]=acc[j][6]+x1.z; o[7]=acc[j][7]+x1.w;
    float s1=0.f, s2=0.f;
    #pragma unroll
    for (int i=0;i<8;i++){ s1 += o[i]; s2 = fmaf(o[i],o[i],s2); }
    #pragma unroll
    for (int m=1;m<16;m<<=1){ s1 += __shfl_xor(s1,m,64); s2 += __shfl_xor(s2,m,64); }
    const float mu = s1*(1.0f/DMODEL);
    const float var = s2*(1.0f/DMODEL) - mu*mu;
    const float rs = rsqrtf(var + LN_EPS);
    *(float4*)(dst + (size_t)rg*DMODEL + tx*4) = make_float4(
      (o[0]-mu)*rs*g0.x+e0.x, (o[1]-mu)*rs*g0.y+e0.y,
      (o[2]-mu)*rs*g0.z+e0.z, (o[3]-mu)*rs*g0.w+e0.w);
    *(float4*)(dst + (size_t)rg*DMODEL + 64 + tx*4) = make_float4(
      (o[4]-mu)*rs*g1.x+e1.x, (o[5]-mu)*rs*g1.y+e1.y,
      (o[6]-mu)*rs*g1.z+e1.z, (o[7]-mu)*rs*g1.w+e1.w);
  }
}

// ================= K5a: FFN1 + ReLU, 64x64 tile GEMM =================
// M=8192, N=256, K=128. grid (128, 4).
__global__ __launch_bounds__(256) void k5a_ffn1(
    const float* __restrict__ ofb, const float* __restrict__ obb,
    const float* __restrict__ w1, const float* __restrict__ b1,
    float* __restrict__ hh)
{
  __shared__ float4 as4[64][16];
  __shared__ float4 wt4[64][16];
  const int t = threadIdx.x;
  const int tx = t&15, ty = t>>4;
  const int r0 = blockIdx.x*64;
  const int c0b = blockIdx.y*64;
  const float* wbase = w1 + (size_t)c0b*DMODEL;

  float acc[4][4];
  #pragma unroll
  for (int j=0;j<4;j++){acc[j][0]=acc[j][1]=acc[j][2]=acc[j][3]=0.f;}

  for (int kc=0; kc<DMODEL; kc+=64){
    #pragma unroll
    for (int p=0;p<4;p++){
      const int row = p*16 + ty;
      const int fs = tx ^ ((row>>2)&15);
      const size_t off = (size_t)(r0+row)*DMODEL + kc + tx*4;
      float4 va = *(const float4*)(ofb + off);
      float4 vb = *(const float4*)(obb + off);
      as4[row][fs] = make_float4(va.x+vb.x, va.y+vb.y, va.z+vb.z, va.w+vb.w);
      wt4[row][fs] = *(const float4*)(wbase + (size_t)row*DMODEL + kc + tx*4);
    }
    __syncthreads();
    #pragma unroll 8
    for (int f=0; f<16; f++){
      float4 a0 = as4[ty*4+0][f^ty];
      float4 a1 = as4[ty*4+1][f^ty];
      float4 a2 = as4[ty*4+2][f^ty];
      float4 a3 = as4[ty*4+3][f^ty];
      float4 b0 = wt4[tx*4+0][f^tx];
      float4 b1 = wt4[tx*4+1][f^tx];
      float4 b2 = wt4[tx*4+2][f^tx];
      float4 b3 = wt4[tx*4+3][f^tx];
      DOT4(acc[0][0],a0,b0); DOT4(acc[0][1],a0,b1); DOT4(acc[0][2],a0,b2); DOT4(acc[0][3],a0,b3);
      DOT4(acc[1][0],a1,b0); DOT4(acc[1][1],a1,b1); DOT4(acc[1][2],a1,b2); DOT4(acc[1][3],a1,b3);
      DOT4(acc[2][0],a2,b0); DOT4(acc[2][1],a2,b1); DOT4(acc[2][2],a2,b2); DOT4(acc[2][3],a2,b3);
      DOT4(acc[3][0],a3,b0); DOT4(acc[3][1],a3,b1); DOT4(acc[3][2],a3,b2); DOT4(acc[3][3],a3,b3);
    }
    __syncthreads();
  }
  const float4 bb = *(const float4*)(b1 + c0b + tx*4);
  #pragma unroll
  for (int j=0;j<4;j++){
    const int rg = r0 + ty*4 + j;
    *(float4*)(hh + (size_t)rg*DFF + c0b + tx*4) = make_float4(
      fmaxf(acc[j][0]+bb.x,0.f), fmaxf(acc[j][1]+bb.y,0.f),
      fmaxf(acc[j][2]+bb.z,0.f), fmaxf(acc[j][3]+bb.w,0.f));
  }
}

// ================= K5b: FFN2 + residual + final LN =================
// 32 rows x 128 cols, K=256 chunks of 64. grid (256).
__global__ __launch_bounds__(256) void k5b_ffn2(
    const float* __restrict__ hh, const float* __restrict__ ofb, const float* __restrict__ obb,
    const float* __restrict__ w2, const float* __restrict__ b2,
    const float* __restrict__ lg, const float* __restrict__ lb,
    float* __restrict__ dout)
{
  __shared__ float4 hs4[32][16];
  __shared__ float4 wt4[128][16];
  const int t = threadIdx.x;
  const int tx = t&15, ty = t>>4;
  const int r0 = blockIdx.x*32;

  float acc[2][8];
  #pragma unroll
  for (int j=0;j<2;j++)
    #pragma unroll
    for (int i=0;i<8;i++) acc[j][i]=0.f;

  for (int kc=0; kc<DFF; kc+=64){
    #pragma unroll
    for (int s=0;s<2;s++){
      const int row = s*16 + ty;
      hs4[row][tx ^ ((row>>2)&15)] = *(const float4*)(hh + (size_t)(r0+row)*DFF + kc + tx*4);
    }
    #pragma unroll
    for (int s=0;s<8;s++){
      const int row = s*16 + ty;
      wt4[row][tx ^ ((row>>2)&15)] = *(const float4*)(w2 + (size_t)row*DFF + kc + tx*4);
    }
    __syncthreads();
    const int gk = (ty*2)>>2;
    #pragma unroll 8
    for (int f=0; f<16; f++){
      float4 a0 = hs4[ty*2+0][f^gk];
      float4 a1 = hs4[ty*2+1][f^gk];
      float4 b0 = wt4[tx*4+0][f^tx];
      float4 b1 = wt4[tx*4+1][f^tx];
      float4 b2v = wt4[tx*4+2][f^tx];
      float4 b3 = wt4[tx*4+3][f^tx];
      float4 b4 = wt4[64+tx*4+0][f^tx];
      float4 b5 = wt4[64+tx*4+1][f^tx];
      float4 b6 = wt4[64+tx*4+2][f^tx];
      float4 b7 = wt4[64+tx*4+3][f^tx];
      DOT4(acc[0][0],a0,b0); DOT4(acc[0][1],a0,b1); DOT4(acc[0][2],a0,b2v); DOT4(acc[0][3],a0,b3);
      DOT4(acc[0][4],a0,b4); DOT4(acc[0][5],a0,b5); DOT4(acc[0][6],a0,b6); DOT4(acc[0][7],a0,b7);
      DOT4(acc[1][0],a1,b0); DOT4(acc[1][1],a1,b1); DOT4(acc[1][2],a1,b2v); DOT4(acc[1][3],a1,b3);
      DOT4(acc[1][4],a1,b4); DOT4(acc[1][5],a1,b5); DOT4(acc[1][6],a1,b6); DOT4(acc[1][7],a1,b7);
    }
    __syncthreads();
  }
  const float4 ba = *(const float4*)(b2 + tx*4);
  const float4 bbq = *(const float4*)(b2 + 64 + tx*4);
  const float4 g0 = *(const float4*)(lg + tx*4);
  const float4 g1 = *(const float4*)(lg + 64 + tx*4);
  const float4 e0 = *(const float4*)(lb + tx*4);
  const float4 e1 = *(const float4*)(lb + 64 + tx*4);
  #pragma unroll
  for (int j=0;j<2;j++){
    const int rg = r0 + ty*2 + j;
    float4 rA = *(const float4*)(ofb + (size_t)rg*DMODEL + tx*4);
    float4 rB = *(const float4*)(obb + (size_t)rg*DMODEL + tx*4);
    float4 rC = *(const float4*)(ofb + (size_t)rg*DMODEL + 64 + tx*4);
    float4 rD = *(const float4*)(obb + (size_t)rg*DMODEL + 64 + tx*4);
    float o[8];
    o[0]=acc[j][0]+ba.x+rA.x+rB.x; o[1]=acc[j][1]+ba.y+rA.y+rB.y;
    o[2]=acc[j][2]+ba.z+rA.z+rB.z; o[3]=acc[j][3]+ba.w+rA.w+rB.w;
    o[4]=acc[j][4]+bbq.x+rC.x+rD.x; o[5]=acc[j][5]+bbq.y+rC.y+rD.y;
    o[6]=acc[j][6]+bbq.z+rC.z+rD.z; o[7]=acc[j][7]+bbq.w+rC.w+rD.w;
    float s1=0.f, s2=0.f;
    #pragma unroll
    for (int i=0;i<8;i++){ s1 += o[i]; s2 = fmaf(o[i],o[i],s2); }
    #pragma unroll
    for (int m=1;m<16;m<<=1){ s1 += __shfl_xor(s1,m,64); s2 += __shfl_xor(s2,m,64); }
    const float mu = s1*(1.0f/DMODEL);
    const float var = s2*(1.0f/DMODEL) - mu*mu;
    const float rs = rsqrtf(var + LN_EPS);
    *(float4*)(dout + (size_t)rg*DMODEL + tx*4) = make_float4(
      (o[0]-mu)*rs*g0.x+e0.x, (o[1]-mu)*rs*g0.y+e0.y,
      (o[2]-mu)*rs*g0.z+e0.z, (o[3]-mu)*rs*g0.w+e0.w);
    *(float4*)(dout + (size_t)rg*DMODEL + 64 + tx*4) = make_float4(
      (o[4]-mu)*rs*g1.x+e1.x, (o[5]-mu)*rs*g1.y+e1.y,
      (o[6]-mu)*rs*g1.z+e1.z, (o[7]-mu)*rs*g1.w+e1.w);
  }
}

extern "C" void kernel_launch(void* const* d_in, const int* in_sizes, int n_in,
                              void* d_out, int out_size, void* d_ws, size_t ws_size,
                              hipStream_t stream)
{
  const float* x      = (const float*)d_in[0];
  const float* mf_inw = (const float*)d_in[1];
  const float* mf_cw  = (const float*)d_in[2];
  const float* mf_cb  = (const float*)d_in[3];
  const float* mf_xp  = (const float*)d_in[4];
  const float* mf_dtw = (const float*)d_in[5];
  const float* mf_dtb = (const float*)d_in[6];
  const float* mf_Al  = (const float*)d_in[7];
  const float* mf_D   = (const float*)d_in[8];
  const float* mf_ow  = (const float*)d_in[9];
  const float* mb_inw = (const float*)d_in[10];
  const float* mb_cw  = (const float*)d_in[11];
  const float* mb_cb  = (const float*)d_in[12];
  const float* mb_xp  = (const float*)d_in[13];
  const float* mb_dtw = (const float*)d_in[14];
  const float* mb_dtb = (const float*)d_in[15];
  const float* mb_Al  = (const float*)d_in[16];
  const float* mb_D   = (const float*)d_in[17];
  const float* mb_ow  = (const float*)d_in[18];
  const float* lfg    = (const float*)d_in[19];
  const float* lfb    = (const float*)d_in[20];
  const float* lbg    = (const float*)d_in[21];
  const float* lbb    = (const float*)d_in[22];
  const float* lng    = (const float*)d_in[23];
  const float* lnb    = (const float*)d_in[24];
  const float* fw1    = (const float*)d_in[25];
  const float* fb1    = (const float*)d_in[26];
  const float* fw2    = (const float*)d_in[27];
  const float* fb2    = (const float*)d_in[28];

  float* ws = (float*)d_ws;
  const size_t n_big = (size_t)2*BATCH*SEQ*DINNER;        // 4,194,304 floats
  const size_t n_bc  = (size_t)2*BATCH*SEQ*32;
  const size_t n_ps  = (size_t)2*BATCH*NCH*DINNER*DSTATE;
  float* xc   = ws;               // [2][B][L][256]; reused as y after k2
  float* zz   = xc + n_big;
  float* uu   = zz + n_big;       // reused as hh after scans
  float* dtt  = uu + n_big;       // reused as ofb/obb after scans
  float* bc   = dtt + n_big;
  float* P    = bc + n_bc;
  float* S    = P + n_ps;
  float* yy   = xc;
  float* ofb  = dtt;
  float* obb  = dtt + (size_t)NROW*DMODEL;
  float* hh   = uu;

  k1_inproj<<<dim3(NROW/64, 16), 256, 0, stream>>>(x, mf_inw, mb_inw, xc, zz);
  k2_conv_xproj<<<dim3(SEQ/16, BATCH, 2), 256, 0, stream>>>(xc,
      mf_cw, mf_cb, mb_cw, mb_cb, mf_xp, mb_xp,
      mf_dtw, mf_dtb, mb_dtw, mb_dtb, uu, dtt, bc);
  k3_scan1<<<dim3(NCH, BATCH, 2), 256, 0, stream>>>(uu, dtt, bc, mf_Al, mb_Al, P, S);
  k3_scan2<<<dim3(DINNER/16, BATCH, 2), 256, 0, stream>>>(P, S);
  k3_scan3<<<dim3(NCH, BATCH, 2), 256, 0, stream>>>(uu, dtt, bc, mf_Al, mb_Al, mf_D, mb_D, S, yy);
  k4_outproj_ln<<<dim3(NROW/32, 2), 256, 0, stream>>>(yy, zz, x, mf_ow, mb_ow,
      lfg, lfb, lbg, lbb, ofb, obb);
  k5a_ffn1<<<dim3(NROW/64, DFF/64), 256, 0, stream>>>(ofb, obb, fw1, fb1, hh);
  k5b_ffn2<<<dim3(NROW/32), 256, 0, stream>>>(hh, ofb, obb, fw2, fb2, lng, lnb, (float*)d_out);
}